// Round 12
// baseline (280.057 us; speedup 1.0000x reference)
//
#include <hip/hip_runtime.h>

#define NPIX 36864   // 192*192

typedef __attribute__((ext_vector_type(8))) short short8;
typedef __attribute__((ext_vector_type(4))) short short4v;
typedef __attribute__((ext_vector_type(4))) float float4v;

__device__ inline unsigned short f2b(float x) {
    unsigned int u = __float_as_uint(x);
    unsigned int r = (u + 0x7FFFu + ((u >> 16) & 1u)) >> 16;
    return (unsigned short)r;
}
__device__ inline float b2f(unsigned short h) {
    return __uint_as_float(((unsigned int)h) << 16);
}

// ---------------------------------------------------------------- fused weight-prep + x cast
//  wb layout (shorts):
//  [0      ) dw_w2 [256][64]        n=16384
//  [16384  ) pw_w2 [256][64]        n=16384
//  [32768  ) dw_w3 [576][256]       n=147456   } combined [768][256]
//  [180224 ) pw_w3 [192][256]       n=49152    }
//  [229376 ) sigW1t [9][64][64]     n=36864   (tap-major)
//  [266240 ) sigW2t [9][64][64]     n=36864
//  [303104 ) sigW3t [9][16][64]     n=9216    (oc padded 2->16 with zeros)
#define WB_TOTAL 312320
#define XCAST_N  1179648   // 2*64*9216
__global__ __launch_bounds__(256) void prep_all(
    const float* __restrict__ dw2, const float* __restrict__ dw3,
    const float* __restrict__ pw2, const float* __restrict__ pw3,
    const float* __restrict__ sw1, const float* __restrict__ sw2,
    const float* __restrict__ sw3, unsigned short* __restrict__ wb,
    const float* __restrict__ x, unsigned short* __restrict__ xb)
{
    int i = blockIdx.x * 256 + threadIdx.x;
    if (i >= WB_TOTAL) {
        int j = i - WB_TOTAL;
        if (j < XCAST_N) xb[j] = f2b(x[j]);
        return;
    }
    unsigned short v;
    if (i < 16384)        v = f2b(dw2[i]);
    else if (i < 32768)   v = f2b(pw2[i - 16384]);
    else if (i < 180224)  v = f2b(dw3[i - 32768]);
    else if (i < 229376)  v = f2b(pw3[i - 180224]);
    else if (i < 266240) { int j = i - 229376; int t = j / 4096, r = j % 4096, oc = r / 64, ic = r % 64;
                           v = f2b(sw1[(oc * 64 + ic) * 9 + t]); }
    else if (i < 303104) { int j = i - 266240; int t = j / 4096, r = j % 4096, oc = r / 64, ic = r % 64;
                           v = f2b(sw2[(oc * 64 + ic) * 9 + t]); }
    else                 { int j = i - 303104; int t = j / 1024, r = j % 1024, oc = r / 64, ic = r % 64;
                           v = (oc < 2) ? f2b(sw3[(oc * 64 + ic) * 9 + t]) : (unsigned short)0; }
    wb[i] = v;
}

// ---------------------------------------------------------------- fused MLP chain, px-tile 32 (high occupancy)
// grid (1152 px-tiles of 32, 4 units). unit 0..2: chain0 (dw) l3 chunk u; unit 3: chain1 (pw).
// LDS: h2s [32 chunks][32 px][8] = 16 KB; h1s [8][32][8] = 4 KB aliased with Ts [64][40] = 5.1 KB.
// Total 21.1 KB -> 7 blocks/CU (28 waves/CU).
__global__ __launch_bounds__(256) void mlp_fused(
    const float* __restrict__ pose,
    const float* __restrict__ w1A, const float* __restrict__ b1A,
    const float* __restrict__ w1B, const float* __restrict__ b1B,
    const unsigned short* __restrict__ w2A, const unsigned short* __restrict__ w2B,
    const float* __restrict__ b2A, const float* __restrict__ b2B,
    const unsigned short* __restrict__ w33,
    const float* __restrict__ b3A, const float* __restrict__ b3B,
    unsigned short* __restrict__ outA, unsigned short* __restrict__ outB)
{
    __shared__ unsigned short sh[32 * 256 + 2560];   // h2s + max(h1s, Ts)
    unsigned short* h2s = sh;
    unsigned short* h1s = sh + 32 * 256;
    unsigned short* Ts  = h1s;
    const int tid = threadIdx.x;
    const int u = blockIdx.y;                    // 0..3
    const int chain = (u == 3) ? 1 : 0;
    const int px0 = blockIdx.x * 32;
    const int w = tid >> 6, l = tid & 63;
    const int ln = l & 15, lkg = l >> 4, lk = lkg * 8;
    const float* w1 = chain ? w1B : w1A;
    const float* b1 = chain ? b1B : b1A;
    const unsigned short* w2 = chain ? w2B : w2A;
    const float* b2 = chain ? b2B : b2A;
    // ---- layer 1: 3 -> 64; thread = (8 oc, 1 px); chunk-major b128 store
    {
        int pxl = l & 31, rep = l >> 5;
        int px = px0 + pxl;
        float p0 = pose[px], p1 = pose[NPIX + px], p2 = pose[2 * NPIX + px];
        short8 s0;
        #pragma unroll
        for (int j = 0; j < 8; ++j) {
            int oc = w * 16 + rep * 8 + j;
            float v = b1[oc] + w1[oc * 3] * p0 + w1[oc * 3 + 1] * p1 + w1[oc * 3 + 2] * p2;
            s0[j] = (short)f2b(fmaxf(v, 0.f));
        }
        *(short8*)&h1s[(w * 2 + rep) * 256 + pxl * 8] = s0;
    }
    __syncthreads();
    // ---- layer 2: 64 -> 256 MFMA; chunk-major h2 writes
    {
        short8 b0v[2], b1v[2];
        #pragma unroll
        for (int nt = 0; nt < 2; ++nt) {
            b0v[nt] = *(const short8*)&h1s[(lkg    ) * 256 + (nt * 16 + ln) * 8];
            b1v[nt] = *(const short8*)&h1s[(4 + lkg) * 256 + (nt * 16 + ln) * 8];
        }
        float4v acc[4][2] = {};
        #pragma unroll
        for (int mt = 0; mt < 4; ++mt) {
            int ocr = w * 64 + mt * 16 + ln;
            short8 a0 = *(const short8*)&w2[(size_t)ocr * 64 + lk];
            short8 a1 = *(const short8*)&w2[(size_t)ocr * 64 + 32 + lk];
            #pragma unroll
            for (int nt = 0; nt < 2; ++nt) {
                acc[mt][nt] = __builtin_amdgcn_mfma_f32_16x16x32_bf16(a0, b0v[nt], acc[mt][nt], 0, 0, 0);
                acc[mt][nt] = __builtin_amdgcn_mfma_f32_16x16x32_bf16(a1, b1v[nt], acc[mt][nt], 0, 0, 0);
            }
        }
        __syncthreads();   // h1s reads done (Ts alias safe later)
        #pragma unroll
        for (int mt = 0; mt < 4; ++mt) {
            int ocb = w * 64 + mt * 16 + lkg * 4;
            int chk = ocb >> 3, pos = (lkg & 1) * 4;
            float bv0 = b2[ocb + 0], bv1 = b2[ocb + 1], bv2 = b2[ocb + 2], bv3 = b2[ocb + 3];
            #pragma unroll
            for (int nt = 0; nt < 2; ++nt) {
                int pxl = nt * 16 + ln;
                short4v pk;
                pk[0] = (short)f2b(fmaxf(acc[mt][nt][0] + bv0, 0.f));
                pk[1] = (short)f2b(fmaxf(acc[mt][nt][1] + bv1, 0.f));
                pk[2] = (short)f2b(fmaxf(acc[mt][nt][2] + bv2, 0.f));
                pk[3] = (short)f2b(fmaxf(acc[mt][nt][3] + bv3, 0.f));
                *(short4v*)&h2s[chk * 256 + pxl * 8 + pos] = pk;
            }
        }
    }
    __syncthreads();     // h2s ready
    // ---- layer 3: one 192-row chunk (in-loop L2-hot weight loads)
    const int rowbase = chain ? 576 : u * 192;   // row into w33
    const int obase   = chain ? 0 : u * 192;     // row into output
    const float* b3 = chain ? b3B : b3A;
    unsigned short* outp = chain ? outB : outA;
    float4v acc[3][2] = {};
    const int r0 = rowbase + w * 48 + ln;
    #pragma unroll
    for (int kc = 0; kc < 8; ++kc) {
        short8 a0 = *(const short8*)&w33[(size_t)(r0 +  0) * 256 + kc * 32 + lk];
        short8 a1 = *(const short8*)&w33[(size_t)(r0 + 16) * 256 + kc * 32 + lk];
        short8 a2 = *(const short8*)&w33[(size_t)(r0 + 32) * 256 + kc * 32 + lk];
        #pragma unroll
        for (int nt = 0; nt < 2; ++nt) {
            short8 b = *(const short8*)&h2s[(kc * 4 + lkg) * 256 + (nt * 16 + ln) * 8];
            acc[0][nt] = __builtin_amdgcn_mfma_f32_16x16x32_bf16(a0, b, acc[0][nt], 0, 0, 0);
            acc[1][nt] = __builtin_amdgcn_mfma_f32_16x16x32_bf16(a1, b, acc[1][nt], 0, 0, 0);
            acc[2][nt] = __builtin_amdgcn_mfma_f32_16x16x32_bf16(a2, b, acc[2][nt], 0, 0, 0);
        }
    }
    // ---- epilogue: per-mt 64-row transpose through Ts (aliases h1s), coalesced stores
    #pragma unroll
    for (int mt = 0; mt < 3; ++mt) {
        __syncthreads();
        {
            int tr = w * 16 + lkg * 4;
            #pragma unroll
            for (int r = 0; r < 4; ++r) {
                float bv = b3[obase + w * 48 + mt * 16 + lkg * 4 + r];
                #pragma unroll
                for (int nt = 0; nt < 2; ++nt)
                    Ts[(tr + r) * 40 + nt * 16 + ln] = f2b(acc[mt][nt][r] + bv);
            }
        }
        __syncthreads();
        {
            int row = tid >> 2, pc = (tid & 3) * 8;
            int gr = obase + (row >> 4) * 48 + mt * 16 + (row & 15);
            *(short8*)&outp[(size_t)gr * NPIX + px0 + pc] = *(const short8*)&Ts[row * 40 + pc];
        }
    }
}

// ---------------------------------------------------------------- bf16 MFMA 3x3 conv, 2-row tiles
template<int MT>
__global__ __launch_bounds__(256) void conv3x3_mfma(
    const unsigned short* __restrict__ act, const unsigned short* __restrict__ wgt,
    const float* __restrict__ bias, unsigned short* __restrict__ out,
    int relu)
{
    constexpr int SP = 72;
    constexpr int OCP = MT * 16;
    __shared__ unsigned short Bs[4 * 66 * SP];   // 38016 B
    const int tid = threadIdx.x;
    int bx = blockIdx.x;
    const int xt = bx % 3; bx /= 3;
    const int yg = bx % 96; const int b = bx / 96;
    const int y0 = yg * 2;
    const int x0 = xt * 64;
    const size_t actb = (size_t)b * NPIX * 64;
    const int w = tid >> 6, l = tid & 63;
    const int ln = l & 15, lkg = l >> 4, lk = lkg * 8;
    const int mt = (MT == 4) ? w : 0;
    short8 Wr[9][2];
    #pragma unroll
    for (int t = 0; t < 9; ++t)
        #pragma unroll
        for (int hh = 0; hh < 2; ++hh)
            Wr[t][hh] = *(const short8*)&wgt[((size_t)t * OCP + mt * 16 + ln) * 64 + hh * 32 + lk];
    for (int s = tid; s < 264; s += 256) {
        int r = s / 66, i = s % 66;
        int yy = y0 + r - 1, xx = x0 + i - 1;
        unsigned short* dst = &Bs[(r * 66 + i) * SP];
        if (yy >= 0 && yy < 192 && xx >= 0 && xx < 192) {
            const unsigned short* src = &act[actb + (size_t)(yy * 192 + xx) * 64];
            #pragma unroll
            for (int j = 0; j < 8; ++j) *(short8*)(dst + j * 8) = *(const short8*)(src + j * 8);
        } else {
            short8 z = {};
            #pragma unroll
            for (int j = 0; j < 8; ++j) *(short8*)(dst + j * 8) = z;
        }
    }
    __syncthreads();
    const int NT = (MT == 4) ? 4 : 1;
    const int ntb = (MT == 4) ? 0 : w;
    float4v acc[2][4] = {};
    #pragma unroll
    for (int t = 0; t < 9; ++t) {
        const int r = t / 3, dx = t % 3;
        #pragma unroll
        for (int hh = 0; hh < 2; ++hh) {
            #pragma unroll
            for (int o = 0; o < 2; ++o) {
                #pragma unroll
                for (int n = 0; n < 4; ++n) {
                    if (n >= NT) break;
                    int slot = (o + r) * 66 + (ntb + n) * 16 + ln + dx;
                    short8 bf = *(const short8*)&Bs[slot * SP + hh * 32 + lk];
                    acc[o][n] = __builtin_amdgcn_mfma_f32_16x16x32_bf16(Wr[t][hh], bf, acc[o][n], 0, 0, 0);
                }
            }
        }
    }
    #pragma unroll
    for (int o = 0; o < 2; ++o) {
        #pragma unroll
        for (int n = 0; n < 4; ++n) {
            if (n >= NT) break;
            int px = (y0 + o) * 192 + x0 + (ntb + n) * 16 + ln;
            if (MT == 4) {
                int oc = mt * 16 + lkg * 4;
                float v0 = acc[o][n][0] + bias[oc + 0];
                float v1 = acc[o][n][1] + bias[oc + 1];
                float v2 = acc[o][n][2] + bias[oc + 2];
                float v3 = acc[o][n][3] + bias[oc + 3];
                if (relu) { v0 = fmaxf(v0, 0.f); v1 = fmaxf(v1, 0.f); v2 = fmaxf(v2, 0.f); v3 = fmaxf(v3, 0.f); }
                uint2 pk;
                pk.x = (unsigned int)f2b(v0) | (((unsigned int)f2b(v1)) << 16);
                pk.y = (unsigned int)f2b(v2) | (((unsigned int)f2b(v3)) << 16);
                *(uint2*)&out[((size_t)b * NPIX + px) * 64 + oc] = pk;
            } else if (lkg == 0) {
                float v0 = acc[o][n][0] + bias[0];
                float v1 = acc[o][n][1] + bias[1];
                out[((size_t)b * 2 + 0) * NPIX + px] = f2b(v0);
                out[((size_t)b * 2 + 1) * NPIX + px] = f2b(v1);
            }
        }
    }
}

// ---------------------------------------------------------------- padded-plane LDS staging helper
#define PLSZ 10192   // 98*104
__device__ inline void stage_planes(const unsigned short* __restrict__ xb, int c,
                                    unsigned short* __restrict__ pl, int tid)
{
    short8 z = {};
    short8* pf = (short8*)pl;
    for (int i = tid; i < (2 * PLSZ) / 8; i += 256) pf[i] = z;
    __syncthreads();
    #pragma unroll
    for (int b = 0; b < 2; ++b) {
        const unsigned short* xp = xb + (size_t)(b * 64 + c) * 9216;
        unsigned short* pb = pl + b * PLSZ;
        for (int i = tid; i < 96 * 12; i += 256) {
            int row = i / 12, ch = i % 12;
            const short4v* src = (const short4v*)&xp[row * 96 + ch * 8];
            unsigned short* d = &pb[(row + 1) * 104 + 4 + ch * 8];
            *(short4v*)d = src[0];
            *(short4v*)(d + 4) = src[1];
        }
    }
    __syncthreads();
}

// ---------------------------------------------------------------- mean: padded LDS plane gather
__global__ __launch_bounds__(256) void mean_k(
    const unsigned short* __restrict__ xb, const int* __restrict__ imy, const int* __restrict__ imx,
    const unsigned short* __restrict__ dw, unsigned short* __restrict__ mean_cm)
{
    __shared__ unsigned short pl[2 * PLSZ];
    const int c = blockIdx.y;
    const int px0 = blockIdx.x * 1024;
    const int tid = threadIdx.x;
    stage_planes(xb, c, pl, tid);
    #pragma unroll
    for (int q = 0; q < 4; ++q) {
        int px = px0 + q * 256 + tid;
        int base = imy[px] * 104 + imx[px] + 3;
        float wk[9];
        {
            float d[9];
            #pragma unroll
            for (int k = 0; k < 9; ++k) d[k] = b2f(dw[(size_t)(c * 9 + k) * NPIX + px]);
            float m = d[0];
            #pragma unroll
            for (int k = 1; k < 9; ++k) m = fmaxf(m, d[k]);
            float s = 0.f;
            #pragma unroll
            for (int k = 0; k < 9; ++k) { wk[k] = __expf(d[k] - m); s += wk[k]; }
            float inv = 1.f / s;
            #pragma unroll
            for (int k = 0; k < 9; ++k) wk[k] *= inv;
        }
        #pragma unroll
        for (int b = 0; b < 2; ++b) {
            const unsigned short* pb = pl + b * PLSZ;
            float a = 0.f;
            #pragma unroll
            for (int k = 0; k < 9; ++k)
                a += wk[k] * b2f(pb[base + (k / 3) * 104 + (k % 3)]);
            mean_cm[(size_t)(b * 64 + c) * NPIX + px] = f2b(a);
        }
    }
}

// ---------------------------------------------------------------- transpose [2][64][NPIX] -> [2][NPIX][64]
__global__ __launch_bounds__(256) void tr_k(
    const unsigned short* __restrict__ in, unsigned short* __restrict__ out)
{
    __shared__ unsigned short T[64 * 68];
    int px0 = blockIdx.x * 64;
    int b = blockIdx.y;
    int tid = threadIdx.x;
    for (int i = tid; i < 4096; i += 256) {
        int c = i >> 6, p = i & 63;
        T[p * 68 + c] = in[(size_t)(b * 64 + c) * NPIX + px0 + p];
    }
    __syncthreads();
    for (int i = tid; i < 4096; i += 256) {
        int p = i >> 6, c = i & 63;
        out[((size_t)b * NPIX + px0 + p) * 64 + c] = T[p * 68 + c];
    }
}

// ---------------------------------------------------------------- xa: padded LDS plane gather
__global__ __launch_bounds__(256) void xa_k(
    const unsigned short* __restrict__ xb, const int* __restrict__ imy, const int* __restrict__ imx,
    const unsigned short* __restrict__ dw, const unsigned short* __restrict__ mean_cm,
    const unsigned short* __restrict__ sigma, unsigned short* __restrict__ xab)
{
    __shared__ unsigned short pl[2 * PLSZ];
    const int c = blockIdx.y;
    const int px0 = blockIdx.x * 1024;
    const int tid = threadIdx.x;
    stage_planes(xb, c, pl, tid);
    #pragma unroll
    for (int q = 0; q < 4; ++q) {
        int px = px0 + q * 256 + tid;
        int base = imy[px] * 104 + imx[px] + 3;
        float d[9];
        #pragma unroll
        for (int k = 0; k < 9; ++k) d[k] = b2f(dw[(size_t)(c * 9 + k) * NPIX + px]);
        #pragma unroll
        for (int b = 0; b < 2; ++b) {
            const unsigned short* pb = pl + b * PLSZ;
            float mn = b2f(mean_cm[(size_t)(b * 64 + c) * NPIX + px]);
            float sd = b2f(sigma[((size_t)b * 2 + 0) * NPIX + px]);
            float sr = b2f(sigma[((size_t)b * 2 + 1) * NPIX + px]);
            float h[9], bw[9];
            #pragma unroll
            for (int k = 0; k < 9; ++k) {
                h[k] = b2f(pb[base + (k / 3) * 104 + (k % 3)]);
                bw[k] = sd * d[k] + sr * fabsf(h[k] - mn);
            }
            float m = bw[0];
            #pragma unroll
            for (int k = 1; k < 9; ++k) m = fmaxf(m, bw[k]);
            float s = 0.f, a = 0.f;
            #pragma unroll
            for (int k = 0; k < 9; ++k) { float e = __expf(bw[k] - m); s += e; a += e * h[k]; }
            xab[(size_t)(b * 64 + c) * NPIX + px] = f2b(a / s);
        }
    }
}

// ---------------------------------------------------------------- einsum partials + reduce
__global__ __launch_bounds__(256) void einsum_part(
    const unsigned short* __restrict__ xab, const unsigned short* __restrict__ pw,
    float* __restrict__ part)
{
    int px = blockIdx.x * 256 + threadIdx.x;
    int b = blockIdx.y;
    int c0 = blockIdx.z * 16;
    float a0 = 0.f, a1 = 0.f, a2 = 0.f;
    #pragma unroll
    for (int c = 0; c < 16; ++c) {
        float v = b2f(xab[(size_t)(b * 64 + c0 + c) * NPIX + px]);
        a0 += v * b2f(pw[(size_t)((c0 + c) * 3 + 0) * NPIX + px]);
        a1 += v * b2f(pw[(size_t)((c0 + c) * 3 + 1) * NPIX + px]);
        a2 += v * b2f(pw[(size_t)((c0 + c) * 3 + 2) * NPIX + px]);
    }
    size_t base = ((size_t)blockIdx.z * 6 + b * 3) * NPIX + px;
    part[base + 0 * NPIX] = a0;
    part[base + 1 * NPIX] = a1;
    part[base + 2 * NPIX] = a2;
}

__global__ __launch_bounds__(256) void einsum_red(
    const float* __restrict__ part, float* __restrict__ out)
{
    int i = blockIdx.x * 256 + threadIdx.x;
    float s = part[i] + part[(size_t)6 * NPIX + i] + part[(size_t)12 * NPIX + i] + part[(size_t)18 * NPIX + i];
    out[i] = s;
}

extern "C" void kernel_launch(void* const* d_in, const int* in_sizes, int n_in,
                              void* d_out, int out_size, void* d_ws, size_t ws_size,
                              hipStream_t stream)
{
    (void)in_sizes; (void)n_in; (void)out_size; (void)ws_size;
    const float* x      = (const float*)d_in[0];
    const float* pose   = (const float*)d_in[1];
    const int*   imy    = (const int*)d_in[2];
    const int*   imx    = (const int*)d_in[3];
    const float* sig_w1 = (const float*)d_in[4];
    const float* sig_b1 = (const float*)d_in[5];
    const float* sig_w2 = (const float*)d_in[6];
    const float* sig_b2 = (const float*)d_in[7];
    const float* sig_w3 = (const float*)d_in[8];
    const float* sig_b3 = (const float*)d_in[9];
    const float* dw_w1  = (const float*)d_in[10];
    const float* dw_b1  = (const float*)d_in[11];
    const float* dw_w2  = (const float*)d_in[12];
    const float* dw_b2  = (const float*)d_in[13];
    const float* dw_w3  = (const float*)d_in[14];
    const float* dw_b3  = (const float*)d_in[15];
    const float* pw_w1  = (const float*)d_in[16];
    const float* pw_b1  = (const float*)d_in[17];
    const float* pw_w2  = (const float*)d_in[18];
    const float* pw_b2  = (const float*)d_in[19];
    const float* pw_w3  = (const float*)d_in[20];
    const float* pw_b3  = (const float*)d_in[21];
    float* out = (float*)d_out;

    unsigned short* ws = (unsigned short*)d_ws;
    size_t off = 0;
    unsigned short* wb      = ws + off; off += WB_TOTAL;
    unsigned short* xb16    = ws + off; off += (size_t)XCAST_N;
    unsigned short* dwbuf   = ws + off; off += (size_t)576 * NPIX;      // plane-major
    unsigned short* pwbuf   = ws + off; off += (size_t)192 * NPIX;      // plane-major
    unsigned short* mean_cm = ws + off; off += (size_t)2 * 64 * NPIX;
    unsigned short* mean_pm = ws + off; off += (size_t)2 * NPIX * 64;
    unsigned short* s1      = ws + off; off += (size_t)2 * NPIX * 64;
    unsigned short* s2      = ws + off; off += (size_t)2 * NPIX * 64;
    unsigned short* sigma   = ws + off; off += (size_t)2 * 2 * NPIX;
    unsigned short* xab     = ws + off; off += (size_t)2 * 64 * NPIX;
    off = (off + 1) & ~(size_t)1;
    float* part = (float*)(ws + off);  // 4*6*NPIX floats

    unsigned short* w_dw2 = wb + 0;
    unsigned short* w_pw2 = wb + 16384;
    unsigned short* w_33  = wb + 32768;   // combined [768][256]
    unsigned short* w_s1t = wb + 229376;
    unsigned short* w_s2t = wb + 266240;
    unsigned short* w_s3t = wb + 303104;

    dim3 blk(256);
    prep_all<<<dim3((WB_TOTAL + XCAST_N + 255) / 256), blk, 0, stream>>>(
        dw_w2, dw_w3, pw_w2, pw_w3, sig_w1, sig_w2, sig_w3, wb, x, xb16);
    mlp_fused<<<dim3(1152, 4), blk, 0, stream>>>(
        pose, dw_w1, dw_b1, pw_w1, pw_b1, w_dw2, w_pw2, dw_b2, pw_b2,
        w_33, dw_b3, pw_b3, dwbuf, pwbuf);
    mean_k<<<dim3(36, 64), blk, 0, stream>>>(xb16, imy, imx, dwbuf, mean_cm);
    tr_k<<<dim3(576, 2), blk, 0, stream>>>(mean_cm, mean_pm);
    conv3x3_mfma<4><<<dim3(576), blk, 0, stream>>>(mean_pm, w_s1t, sig_b1, s1, 1);
    conv3x3_mfma<4><<<dim3(576), blk, 0, stream>>>(s1,      w_s2t, sig_b2, s2, 1);
    conv3x3_mfma<1><<<dim3(576), blk, 0, stream>>>(s2,      w_s3t, sig_b3, sigma, 0);
    xa_k<<<dim3(36, 64), blk, 0, stream>>>(xb16, imy, imx, dwbuf, mean_cm, sigma, xab);
    einsum_part<<<dim3(144, 2, 4), blk, 0, stream>>>(xab, pwbuf, part);
    einsum_red<<<dim3(864), blk, 0, stream>>>(part, out);
}

// Round 13
// 250.960 us; speedup vs baseline: 1.1159x; 1.1159x over previous
//
#include <hip/hip_runtime.h>

#define NPIX 36864   // 192*192

typedef __attribute__((ext_vector_type(8))) short short8;
typedef __attribute__((ext_vector_type(4))) short short4v;
typedef __attribute__((ext_vector_type(4))) float float4v;

__device__ inline unsigned short f2b(float x) {
    unsigned int u = __float_as_uint(x);
    unsigned int r = (u + 0x7FFFu + ((u >> 16) & 1u)) >> 16;
    return (unsigned short)r;
}
__device__ inline float b2f(unsigned short h) {
    return __uint_as_float(((unsigned int)h) << 16);
}

// ---------------------------------------------------------------- fused weight-prep + x cast
//  wb layout (shorts):
//  [0      ) dw_w2 [256][64]        n=16384
//  [16384  ) pw_w2 [256][64]        n=16384
//  [32768  ) dw_w3 [576][256]       n=147456   } combined [768][256]
//  [180224 ) pw_w3 [192][256]       n=49152    }
//  [229376 ) sigW1t [9][64][64]     n=36864   (tap-major)
//  [266240 ) sigW2t [9][64][64]     n=36864
//  [303104 ) sigW3t [9][16][64]     n=9216    (oc padded 2->16 with zeros)
#define WB_TOTAL 312320
#define XCAST_N  1179648   // 2*64*9216
__global__ __launch_bounds__(256) void prep_all(
    const float* __restrict__ dw2, const float* __restrict__ dw3,
    const float* __restrict__ pw2, const float* __restrict__ pw3,
    const float* __restrict__ sw1, const float* __restrict__ sw2,
    const float* __restrict__ sw3, unsigned short* __restrict__ wb,
    const float* __restrict__ x, unsigned short* __restrict__ xb)
{
    int i = blockIdx.x * 256 + threadIdx.x;
    if (i >= WB_TOTAL) {
        int j = i - WB_TOTAL;
        if (j < XCAST_N) xb[j] = f2b(x[j]);
        return;
    }
    unsigned short v;
    if (i < 16384)        v = f2b(dw2[i]);
    else if (i < 32768)   v = f2b(pw2[i - 16384]);
    else if (i < 180224)  v = f2b(dw3[i - 32768]);
    else if (i < 229376)  v = f2b(pw3[i - 180224]);
    else if (i < 266240) { int j = i - 229376; int t = j / 4096, r = j % 4096, oc = r / 64, ic = r % 64;
                           v = f2b(sw1[(oc * 64 + ic) * 9 + t]); }
    else if (i < 303104) { int j = i - 266240; int t = j / 4096, r = j % 4096, oc = r / 64, ic = r % 64;
                           v = f2b(sw2[(oc * 64 + ic) * 9 + t]); }
    else                 { int j = i - 303104; int t = j / 1024, r = j % 1024, oc = r / 64, ic = r % 64;
                           v = (oc < 2) ? f2b(sw3[(oc * 64 + ic) * 9 + t]) : (unsigned short)0; }
    wb[i] = v;
}

// ---------------------------------------------------------------- fused MLP chain (R11 best config)
// grid (576 px-tiles of 64, 4 units). unit 0..2: chain0 (dw) l3 chunk u; unit 3: chain1 (pw).
// LDS (chunk-major, conflict-free b128): h2s [32 chunks][64 px][8] = 32 KB;
// h1s [8 chunks][64][8] = 8 KB, aliased with Ts [64][72] = 9.2 KB. Total 41 KB -> 3 blocks/CU.
__global__ __launch_bounds__(256) void mlp_fused(
    const float* __restrict__ pose,
    const float* __restrict__ w1A, const float* __restrict__ b1A,
    const float* __restrict__ w1B, const float* __restrict__ b1B,
    const unsigned short* __restrict__ w2A, const unsigned short* __restrict__ w2B,
    const float* __restrict__ b2A, const float* __restrict__ b2B,
    const unsigned short* __restrict__ w33,
    const float* __restrict__ b3A, const float* __restrict__ b3B,
    unsigned short* __restrict__ outA, unsigned short* __restrict__ outB)
{
    __shared__ unsigned short sh[32 * 512 + 4608];   // h2s + max(h1s, Ts)
    unsigned short* h2s = sh;
    unsigned short* h1s = sh + 32 * 512;
    unsigned short* Ts  = h1s;
    const int tid = threadIdx.x;
    const int u = blockIdx.y;                    // 0..3
    const int chain = (u == 3) ? 1 : 0;
    const int px0 = blockIdx.x * 64;
    const int w = tid >> 6, l = tid & 63;
    const int ln = l & 15, lkg = l >> 4, lk = lkg * 8;
    const float* w1 = chain ? w1B : w1A;
    const float* b1 = chain ? b1B : b1A;
    const unsigned short* w2 = chain ? w2B : w2A;
    const float* b2 = chain ? b2B : b2A;
    // ---- layer 1: 3 -> 64, scalar FMA; packed b128 stores, chunk-major
    {
        int px = px0 + l;
        float p0 = pose[px], p1 = pose[NPIX + px], p2 = pose[2 * NPIX + px];
        short8 s0, s1;
        #pragma unroll
        for (int j = 0; j < 16; ++j) {
            int oc = w * 16 + j;
            float v = b1[oc] + w1[oc * 3] * p0 + w1[oc * 3 + 1] * p1 + w1[oc * 3 + 2] * p2;
            unsigned short uv = f2b(fmaxf(v, 0.f));
            if (j < 8) s0[j] = (short)uv; else s1[j - 8] = (short)uv;
        }
        *(short8*)&h1s[(w * 2 + 0) * 512 + l * 8] = s0;
        *(short8*)&h1s[(w * 2 + 1) * 512 + l * 8] = s1;
    }
    __syncthreads();
    // ---- layer 2: 64 -> 256 MFMA; b-fragments hoisted; chunk-major writes
    {
        short8 b0v[4], b1v[4];
        #pragma unroll
        for (int nt = 0; nt < 4; ++nt) {
            b0v[nt] = *(const short8*)&h1s[(lkg    ) * 512 + (nt * 16 + ln) * 8];
            b1v[nt] = *(const short8*)&h1s[(4 + lkg) * 512 + (nt * 16 + ln) * 8];
        }
        float4v acc[4][4] = {};
        #pragma unroll
        for (int mt = 0; mt < 4; ++mt) {
            int ocr = w * 64 + mt * 16 + ln;
            short8 a0 = *(const short8*)&w2[(size_t)ocr * 64 + lk];
            short8 a1 = *(const short8*)&w2[(size_t)ocr * 64 + 32 + lk];
            #pragma unroll
            for (int nt = 0; nt < 4; ++nt) {
                acc[mt][nt] = __builtin_amdgcn_mfma_f32_16x16x32_bf16(a0, b0v[nt], acc[mt][nt], 0, 0, 0);
                acc[mt][nt] = __builtin_amdgcn_mfma_f32_16x16x32_bf16(a1, b1v[nt], acc[mt][nt], 0, 0, 0);
            }
        }
        __syncthreads();   // h1s reads done (Ts alias safe later)
        #pragma unroll
        for (int mt = 0; mt < 4; ++mt) {
            int ocb = w * 64 + mt * 16 + lkg * 4;
            int chk = ocb >> 3, pos = (lkg & 1) * 4;
            float bv0 = b2[ocb + 0], bv1 = b2[ocb + 1], bv2 = b2[ocb + 2], bv3 = b2[ocb + 3];
            #pragma unroll
            for (int nt = 0; nt < 4; ++nt) {
                int pxl = nt * 16 + ln;
                short4v pk;
                pk[0] = (short)f2b(fmaxf(acc[mt][nt][0] + bv0, 0.f));
                pk[1] = (short)f2b(fmaxf(acc[mt][nt][1] + bv1, 0.f));
                pk[2] = (short)f2b(fmaxf(acc[mt][nt][2] + bv2, 0.f));
                pk[3] = (short)f2b(fmaxf(acc[mt][nt][3] + bv3, 0.f));
                *(short4v*)&h2s[chk * 512 + pxl * 8 + pos] = pk;
            }
        }
    }
    __syncthreads();     // h2s ready
    // ---- layer 3: one 192-row chunk (in-loop L2-hot weight loads)
    const int rowbase = chain ? 576 : u * 192;   // row into w33
    const int obase   = chain ? 0 : u * 192;     // row into output
    const float* b3 = chain ? b3B : b3A;
    unsigned short* outp = chain ? outB : outA;
    float4v acc[3][4] = {};
    const int r0 = rowbase + w * 48 + ln;
    #pragma unroll
    for (int kc = 0; kc < 8; ++kc) {
        short8 a0 = *(const short8*)&w33[(size_t)(r0 +  0) * 256 + kc * 32 + lk];
        short8 a1 = *(const short8*)&w33[(size_t)(r0 + 16) * 256 + kc * 32 + lk];
        short8 a2 = *(const short8*)&w33[(size_t)(r0 + 32) * 256 + kc * 32 + lk];
        #pragma unroll
        for (int nt = 0; nt < 4; ++nt) {
            short8 b = *(const short8*)&h2s[(kc * 4 + lkg) * 512 + (nt * 16 + ln) * 8];
            acc[0][nt] = __builtin_amdgcn_mfma_f32_16x16x32_bf16(a0, b, acc[0][nt], 0, 0, 0);
            acc[1][nt] = __builtin_amdgcn_mfma_f32_16x16x32_bf16(a1, b, acc[1][nt], 0, 0, 0);
            acc[2][nt] = __builtin_amdgcn_mfma_f32_16x16x32_bf16(a2, b, acc[2][nt], 0, 0, 0);
        }
    }
    // ---- epilogue: per-mt 64-row transpose through Ts (aliases h1s), coalesced stores
    #pragma unroll
    for (int mt = 0; mt < 3; ++mt) {
        __syncthreads();
        {
            int tr = w * 16 + lkg * 4;
            #pragma unroll
            for (int r = 0; r < 4; ++r) {
                float bv = b3[obase + w * 48 + mt * 16 + lkg * 4 + r];
                #pragma unroll
                for (int nt = 0; nt < 4; ++nt)
                    Ts[(tr + r) * 72 + nt * 16 + ln] = f2b(acc[mt][nt][r] + bv);
            }
        }
        __syncthreads();
        for (int i = tid; i < 512; i += 256) {
            int row = i >> 3, pc = (i & 7) * 8;
            int gr = obase + (row >> 4) * 48 + mt * 16 + (row & 15);
            *(short8*)&outp[(size_t)gr * NPIX + px0 + pc] = *(const short8*)&Ts[row * 72 + pc];
        }
    }
}

// ---------------------------------------------------------------- bf16 MFMA 3x3 conv, 2-row tiles
template<int MT>
__global__ __launch_bounds__(256) void conv3x3_mfma(
    const unsigned short* __restrict__ act, const unsigned short* __restrict__ wgt,
    const float* __restrict__ bias, unsigned short* __restrict__ out,
    int relu)
{
    constexpr int SP = 72;
    constexpr int OCP = MT * 16;
    __shared__ unsigned short Bs[4 * 66 * SP];   // 38016 B
    const int tid = threadIdx.x;
    int bx = blockIdx.x;
    const int xt = bx % 3; bx /= 3;
    const int yg = bx % 96; const int b = bx / 96;
    const int y0 = yg * 2;
    const int x0 = xt * 64;
    const size_t actb = (size_t)b * NPIX * 64;
    const int w = tid >> 6, l = tid & 63;
    const int ln = l & 15, lkg = l >> 4, lk = lkg * 8;
    const int mt = (MT == 4) ? w : 0;
    short8 Wr[9][2];
    #pragma unroll
    for (int t = 0; t < 9; ++t)
        #pragma unroll
        for (int hh = 0; hh < 2; ++hh)
            Wr[t][hh] = *(const short8*)&wgt[((size_t)t * OCP + mt * 16 + ln) * 64 + hh * 32 + lk];
    for (int s = tid; s < 264; s += 256) {
        int r = s / 66, i = s % 66;
        int yy = y0 + r - 1, xx = x0 + i - 1;
        unsigned short* dst = &Bs[(r * 66 + i) * SP];
        if (yy >= 0 && yy < 192 && xx >= 0 && xx < 192) {
            const unsigned short* src = &act[actb + (size_t)(yy * 192 + xx) * 64];
            #pragma unroll
            for (int j = 0; j < 8; ++j) *(short8*)(dst + j * 8) = *(const short8*)(src + j * 8);
        } else {
            short8 z = {};
            #pragma unroll
            for (int j = 0; j < 8; ++j) *(short8*)(dst + j * 8) = z;
        }
    }
    __syncthreads();
    const int NT = (MT == 4) ? 4 : 1;
    const int ntb = (MT == 4) ? 0 : w;
    float4v acc[2][4] = {};
    #pragma unroll
    for (int t = 0; t < 9; ++t) {
        const int r = t / 3, dx = t % 3;
        #pragma unroll
        for (int hh = 0; hh < 2; ++hh) {
            #pragma unroll
            for (int o = 0; o < 2; ++o) {
                #pragma unroll
                for (int n = 0; n < 4; ++n) {
                    if (n >= NT) break;
                    int slot = (o + r) * 66 + (ntb + n) * 16 + ln + dx;
                    short8 bf = *(const short8*)&Bs[slot * SP + hh * 32 + lk];
                    acc[o][n] = __builtin_amdgcn_mfma_f32_16x16x32_bf16(Wr[t][hh], bf, acc[o][n], 0, 0, 0);
                }
            }
        }
    }
    #pragma unroll
    for (int o = 0; o < 2; ++o) {
        #pragma unroll
        for (int n = 0; n < 4; ++n) {
            if (n >= NT) break;
            int px = (y0 + o) * 192 + x0 + (ntb + n) * 16 + ln;
            if (MT == 4) {
                int oc = mt * 16 + lkg * 4;
                float v0 = acc[o][n][0] + bias[oc + 0];
                float v1 = acc[o][n][1] + bias[oc + 1];
                float v2 = acc[o][n][2] + bias[oc + 2];
                float v3 = acc[o][n][3] + bias[oc + 3];
                if (relu) { v0 = fmaxf(v0, 0.f); v1 = fmaxf(v1, 0.f); v2 = fmaxf(v2, 0.f); v3 = fmaxf(v3, 0.f); }
                uint2 pk;
                pk.x = (unsigned int)f2b(v0) | (((unsigned int)f2b(v1)) << 16);
                pk.y = (unsigned int)f2b(v2) | (((unsigned int)f2b(v3)) << 16);
                *(uint2*)&out[((size_t)b * NPIX + px) * 64 + oc] = pk;
            } else if (lkg == 0) {
                float v0 = acc[o][n][0] + bias[0];
                float v1 = acc[o][n][1] + bias[1];
                out[((size_t)b * 2 + 0) * NPIX + px] = f2b(v0);
                out[((size_t)b * 2 + 1) * NPIX + px] = f2b(v1);
            }
        }
    }
}

// ---------------------------------------------------------------- padded-plane LDS staging helper
#define PLSZ 10192   // 98*104
__device__ inline void stage_planes(const unsigned short* __restrict__ xb, int c,
                                    unsigned short* __restrict__ pl, int tid)
{
    short8 z = {};
    short8* pf = (short8*)pl;
    for (int i = tid; i < (2 * PLSZ) / 8; i += 256) pf[i] = z;
    __syncthreads();
    #pragma unroll
    for (int b = 0; b < 2; ++b) {
        const unsigned short* xp = xb + (size_t)(b * 64 + c) * 9216;
        unsigned short* pb = pl + b * PLSZ;
        for (int i = tid; i < 96 * 12; i += 256) {
            int row = i / 12, ch = i % 12;
            const short4v* src = (const short4v*)&xp[row * 96 + ch * 8];
            unsigned short* d = &pb[(row + 1) * 104 + 4 + ch * 8];
            *(short4v*)d = src[0];
            *(short4v*)(d + 4) = src[1];
        }
    }
    __syncthreads();
}

// ---------------------------------------------------------------- mean: padded LDS plane gather
__global__ __launch_bounds__(256) void mean_k(
    const unsigned short* __restrict__ xb, const int* __restrict__ imy, const int* __restrict__ imx,
    const unsigned short* __restrict__ dw, unsigned short* __restrict__ mean_cm)
{
    __shared__ unsigned short pl[2 * PLSZ];
    const int c = blockIdx.y;
    const int px0 = blockIdx.x * 1024;
    const int tid = threadIdx.x;
    stage_planes(xb, c, pl, tid);
    #pragma unroll
    for (int q = 0; q < 4; ++q) {
        int px = px0 + q * 256 + tid;
        int base = imy[px] * 104 + imx[px] + 3;
        float wk[9];
        {
            float d[9];
            #pragma unroll
            for (int k = 0; k < 9; ++k) d[k] = b2f(dw[(size_t)(c * 9 + k) * NPIX + px]);
            float m = d[0];
            #pragma unroll
            for (int k = 1; k < 9; ++k) m = fmaxf(m, d[k]);
            float s = 0.f;
            #pragma unroll
            for (int k = 0; k < 9; ++k) { wk[k] = __expf(d[k] - m); s += wk[k]; }
            float inv = 1.f / s;
            #pragma unroll
            for (int k = 0; k < 9; ++k) wk[k] *= inv;
        }
        #pragma unroll
        for (int b = 0; b < 2; ++b) {
            const unsigned short* pb = pl + b * PLSZ;
            float a = 0.f;
            #pragma unroll
            for (int k = 0; k < 9; ++k)
                a += wk[k] * b2f(pb[base + (k / 3) * 104 + (k % 3)]);
            mean_cm[(size_t)(b * 64 + c) * NPIX + px] = f2b(a);
        }
    }
}

// ---------------------------------------------------------------- transpose [2][64][NPIX] -> [2][NPIX][64]
__global__ __launch_bounds__(256) void tr_k(
    const unsigned short* __restrict__ in, unsigned short* __restrict__ out)
{
    __shared__ unsigned short T[64 * 68];
    int px0 = blockIdx.x * 64;
    int b = blockIdx.y;
    int tid = threadIdx.x;
    for (int i = tid; i < 4096; i += 256) {
        int c = i >> 6, p = i & 63;
        T[p * 68 + c] = in[(size_t)(b * 64 + c) * NPIX + px0 + p];
    }
    __syncthreads();
    for (int i = tid; i < 4096; i += 256) {
        int p = i >> 6, c = i & 63;
        out[((size_t)b * NPIX + px0 + p) * 64 + c] = T[p * 68 + c];
    }
}

// ---------------------------------------------------------------- xa: padded LDS plane gather
__global__ __launch_bounds__(256) void xa_k(
    const unsigned short* __restrict__ xb, const int* __restrict__ imy, const int* __restrict__ imx,
    const unsigned short* __restrict__ dw, const unsigned short* __restrict__ mean_cm,
    const unsigned short* __restrict__ sigma, unsigned short* __restrict__ xab)
{
    __shared__ unsigned short pl[2 * PLSZ];
    const int c = blockIdx.y;
    const int px0 = blockIdx.x * 1024;
    const int tid = threadIdx.x;
    stage_planes(xb, c, pl, tid);
    #pragma unroll
    for (int q = 0; q < 4; ++q) {
        int px = px0 + q * 256 + tid;
        int base = imy[px] * 104 + imx[px] + 3;
        float d[9];
        #pragma unroll
        for (int k = 0; k < 9; ++k) d[k] = b2f(dw[(size_t)(c * 9 + k) * NPIX + px]);
        #pragma unroll
        for (int b = 0; b < 2; ++b) {
            const unsigned short* pb = pl + b * PLSZ;
            float mn = b2f(mean_cm[(size_t)(b * 64 + c) * NPIX + px]);
            float sd = b2f(sigma[((size_t)b * 2 + 0) * NPIX + px]);
            float sr = b2f(sigma[((size_t)b * 2 + 1) * NPIX + px]);
            float h[9], bw[9];
            #pragma unroll
            for (int k = 0; k < 9; ++k) {
                h[k] = b2f(pb[base + (k / 3) * 104 + (k % 3)]);
                bw[k] = sd * d[k] + sr * fabsf(h[k] - mn);
            }
            float m = bw[0];
            #pragma unroll
            for (int k = 1; k < 9; ++k) m = fmaxf(m, bw[k]);
            float s = 0.f, a = 0.f;
            #pragma unroll
            for (int k = 0; k < 9; ++k) { float e = __expf(bw[k] - m); s += e; a += e * h[k]; }
            xab[(size_t)(b * 64 + c) * NPIX + px] = f2b(a / s);
        }
    }
}

// ---------------------------------------------------------------- fused einsum: block = 64 px, 4 c-quarters
__global__ __launch_bounds__(256) void einsum_k(
    const unsigned short* __restrict__ xab, const unsigned short* __restrict__ pw,
    float* __restrict__ out)
{
    __shared__ float red[3][4][64];
    const int tid = threadIdx.x;
    const int pxl = tid & 63, cq = tid >> 6;
    const int px = blockIdx.x * 64 + pxl;
    const int b = blockIdx.y;
    float a0 = 0.f, a1 = 0.f, a2 = 0.f;
    #pragma unroll
    for (int ci = 0; ci < 16; ++ci) {
        int c = cq * 16 + ci;
        float v = b2f(xab[(size_t)(b * 64 + c) * NPIX + px]);
        a0 += v * b2f(pw[(size_t)(c * 3 + 0) * NPIX + px]);
        a1 += v * b2f(pw[(size_t)(c * 3 + 1) * NPIX + px]);
        a2 += v * b2f(pw[(size_t)(c * 3 + 2) * NPIX + px]);
    }
    red[0][cq][pxl] = a0;
    red[1][cq][pxl] = a1;
    red[2][cq][pxl] = a2;
    __syncthreads();
    if (cq < 3) {
        float s = red[cq][0][pxl] + red[cq][1][pxl] + red[cq][2][pxl] + red[cq][3][pxl];
        out[((size_t)b * 3 + cq) * NPIX + px] = s;
    }
}

extern "C" void kernel_launch(void* const* d_in, const int* in_sizes, int n_in,
                              void* d_out, int out_size, void* d_ws, size_t ws_size,
                              hipStream_t stream)
{
    (void)in_sizes; (void)n_in; (void)out_size; (void)ws_size;
    const float* x      = (const float*)d_in[0];
    const float* pose   = (const float*)d_in[1];
    const int*   imy    = (const int*)d_in[2];
    const int*   imx    = (const int*)d_in[3];
    const float* sig_w1 = (const float*)d_in[4];
    const float* sig_b1 = (const float*)d_in[5];
    const float* sig_w2 = (const float*)d_in[6];
    const float* sig_b2 = (const float*)d_in[7];
    const float* sig_w3 = (const float*)d_in[8];
    const float* sig_b3 = (const float*)d_in[9];
    const float* dw_w1  = (const float*)d_in[10];
    const float* dw_b1  = (const float*)d_in[11];
    const float* dw_w2  = (const float*)d_in[12];
    const float* dw_b2  = (const float*)d_in[13];
    const float* dw_w3  = (const float*)d_in[14];
    const float* dw_b3  = (const float*)d_in[15];
    const float* pw_w1  = (const float*)d_in[16];
    const float* pw_b1  = (const float*)d_in[17];
    const float* pw_w2  = (const float*)d_in[18];
    const float* pw_b2  = (const float*)d_in[19];
    const float* pw_w3  = (const float*)d_in[20];
    const float* pw_b3  = (const float*)d_in[21];
    float* out = (float*)d_out;

    unsigned short* ws = (unsigned short*)d_ws;
    size_t off = 0;
    unsigned short* wb      = ws + off; off += WB_TOTAL;
    unsigned short* xb16    = ws + off; off += (size_t)XCAST_N;
    unsigned short* dwbuf   = ws + off; off += (size_t)576 * NPIX;      // plane-major
    unsigned short* pwbuf   = ws + off; off += (size_t)192 * NPIX;      // plane-major
    unsigned short* mean_cm = ws + off; off += (size_t)2 * 64 * NPIX;
    unsigned short* mean_pm = ws + off; off += (size_t)2 * NPIX * 64;
    unsigned short* s1      = ws + off; off += (size_t)2 * NPIX * 64;
    unsigned short* s2      = ws + off; off += (size_t)2 * NPIX * 64;
    unsigned short* sigma   = ws + off; off += (size_t)2 * 2 * NPIX;
    unsigned short* xab     = ws + off; off += (size_t)2 * 64 * NPIX;

    unsigned short* w_dw2 = wb + 0;
    unsigned short* w_pw2 = wb + 16384;
    unsigned short* w_33  = wb + 32768;   // combined [768][256]
    unsigned short* w_s1t = wb + 229376;
    unsigned short* w_s2t = wb + 266240;
    unsigned short* w_s3t = wb + 303104;

    dim3 blk(256);
    prep_all<<<dim3((WB_TOTAL + XCAST_N + 255) / 256), blk, 0, stream>>>(
        dw_w2, dw_w3, pw_w2, pw_w3, sig_w1, sig_w2, sig_w3, wb, x, xb16);
    mlp_fused<<<dim3(576, 4), blk, 0, stream>>>(
        pose, dw_w1, dw_b1, pw_w1, pw_b1, w_dw2, w_pw2, dw_b2, pw_b2,
        w_33, dw_b3, pw_b3, dwbuf, pwbuf);
    mean_k<<<dim3(36, 64), blk, 0, stream>>>(xb16, imy, imx, dwbuf, mean_cm);
    tr_k<<<dim3(576, 2), blk, 0, stream>>>(mean_cm, mean_pm);
    conv3x3_mfma<4><<<dim3(576), blk, 0, stream>>>(mean_pm, w_s1t, sig_b1, s1, 1);
    conv3x3_mfma<4><<<dim3(576), blk, 0, stream>>>(s1,      w_s2t, sig_b2, s2, 1);
    conv3x3_mfma<1><<<dim3(576), blk, 0, stream>>>(s2,      w_s3t, sig_b3, sigma, 0);
    xa_k<<<dim3(36, 64), blk, 0, stream>>>(xb16, imy, imx, dwbuf, mean_cm, sigma, xab);
    einsum_k<<<dim3(576, 2), blk, 0, stream>>>(xab, pwbuf, out);
}

// Round 14
// 247.526 us; speedup vs baseline: 1.1314x; 1.0139x over previous
//
#include <hip/hip_runtime.h>

#define NPIX 36864   // 192*192

typedef __attribute__((ext_vector_type(8))) short short8;
typedef __attribute__((ext_vector_type(4))) short short4v;
typedef __attribute__((ext_vector_type(4))) float float4v;

__device__ inline unsigned short f2b(float x) {
    unsigned int u = __float_as_uint(x);
    unsigned int r = (u + 0x7FFFu + ((u >> 16) & 1u)) >> 16;
    return (unsigned short)r;
}
__device__ inline float b2f(unsigned short h) {
    return __uint_as_float(((unsigned int)h) << 16);
}

// ---------------------------------------------------------------- fused weight-prep + x cast
//  wb layout (shorts):
//  [0      ) dw_w2 [256][64]        n=16384
//  [16384  ) pw_w2 [256][64]        n=16384
//  [32768  ) dw_w3 [576][256]       n=147456   } combined [768][256]
//  [180224 ) pw_w3 [192][256]       n=49152    }
//  [229376 ) sigW1t [9][64][64]     n=36864   (tap-major)
//  [266240 ) sigW2t [9][64][64]     n=36864
//  [303104 ) sigW3t [9][16][64]     n=9216    (oc padded 2->16 with zeros)
#define WB_TOTAL 312320
#define XCAST_N  1179648   // 2*64*9216
__global__ __launch_bounds__(256) void prep_all(
    const float* __restrict__ dw2, const float* __restrict__ dw3,
    const float* __restrict__ pw2, const float* __restrict__ pw3,
    const float* __restrict__ sw1, const float* __restrict__ sw2,
    const float* __restrict__ sw3, unsigned short* __restrict__ wb,
    const float* __restrict__ x, unsigned short* __restrict__ xb)
{
    int i = blockIdx.x * 256 + threadIdx.x;
    if (i >= WB_TOTAL) {
        int j = i - WB_TOTAL;
        if (j < XCAST_N) xb[j] = f2b(x[j]);
        return;
    }
    unsigned short v;
    if (i < 16384)        v = f2b(dw2[i]);
    else if (i < 32768)   v = f2b(pw2[i - 16384]);
    else if (i < 180224)  v = f2b(dw3[i - 32768]);
    else if (i < 229376)  v = f2b(pw3[i - 180224]);
    else if (i < 266240) { int j = i - 229376; int t = j / 4096, r = j % 4096, oc = r / 64, ic = r % 64;
                           v = f2b(sw1[(oc * 64 + ic) * 9 + t]); }
    else if (i < 303104) { int j = i - 266240; int t = j / 4096, r = j % 4096, oc = r / 64, ic = r % 64;
                           v = f2b(sw2[(oc * 64 + ic) * 9 + t]); }
    else                 { int j = i - 303104; int t = j / 1024, r = j % 1024, oc = r / 64, ic = r % 64;
                           v = (oc < 2) ? f2b(sw3[(oc * 64 + ic) * 9 + t]) : (unsigned short)0; }
    wb[i] = v;
}

// ---------------------------------------------------------------- fused MLP chain (R11 best config)
// grid (576 px-tiles of 64, 4 units). unit 0..2: chain0 (dw) l3 chunk u; unit 3: chain1 (pw).
// LDS (chunk-major, conflict-free b128): h2s [32 chunks][64 px][8] = 32 KB;
// h1s [8 chunks][64][8] = 8 KB, aliased with Ts [64][72] = 9.2 KB. Total 41 KB -> 3 blocks/CU.
__global__ __launch_bounds__(256) void mlp_fused(
    const float* __restrict__ pose,
    const float* __restrict__ w1A, const float* __restrict__ b1A,
    const float* __restrict__ w1B, const float* __restrict__ b1B,
    const unsigned short* __restrict__ w2A, const unsigned short* __restrict__ w2B,
    const float* __restrict__ b2A, const float* __restrict__ b2B,
    const unsigned short* __restrict__ w33,
    const float* __restrict__ b3A, const float* __restrict__ b3B,
    unsigned short* __restrict__ outA, unsigned short* __restrict__ outB)
{
    __shared__ unsigned short sh[32 * 512 + 4608];   // h2s + max(h1s, Ts)
    unsigned short* h2s = sh;
    unsigned short* h1s = sh + 32 * 512;
    unsigned short* Ts  = h1s;
    const int tid = threadIdx.x;
    const int u = blockIdx.y;                    // 0..3
    const int chain = (u == 3) ? 1 : 0;
    const int px0 = blockIdx.x * 64;
    const int w = tid >> 6, l = tid & 63;
    const int ln = l & 15, lkg = l >> 4, lk = lkg * 8;
    const float* w1 = chain ? w1B : w1A;
    const float* b1 = chain ? b1B : b1A;
    const unsigned short* w2 = chain ? w2B : w2A;
    const float* b2 = chain ? b2B : b2A;
    // ---- layer 1: 3 -> 64, scalar FMA; packed b128 stores, chunk-major
    {
        int px = px0 + l;
        float p0 = pose[px], p1 = pose[NPIX + px], p2 = pose[2 * NPIX + px];
        short8 s0, s1;
        #pragma unroll
        for (int j = 0; j < 16; ++j) {
            int oc = w * 16 + j;
            float v = b1[oc] + w1[oc * 3] * p0 + w1[oc * 3 + 1] * p1 + w1[oc * 3 + 2] * p2;
            unsigned short uv = f2b(fmaxf(v, 0.f));
            if (j < 8) s0[j] = (short)uv; else s1[j - 8] = (short)uv;
        }
        *(short8*)&h1s[(w * 2 + 0) * 512 + l * 8] = s0;
        *(short8*)&h1s[(w * 2 + 1) * 512 + l * 8] = s1;
    }
    __syncthreads();
    // ---- layer 2: 64 -> 256 MFMA; b-fragments hoisted; chunk-major writes
    {
        short8 b0v[4], b1v[4];
        #pragma unroll
        for (int nt = 0; nt < 4; ++nt) {
            b0v[nt] = *(const short8*)&h1s[(lkg    ) * 512 + (nt * 16 + ln) * 8];
            b1v[nt] = *(const short8*)&h1s[(4 + lkg) * 512 + (nt * 16 + ln) * 8];
        }
        float4v acc[4][4] = {};
        #pragma unroll
        for (int mt = 0; mt < 4; ++mt) {
            int ocr = w * 64 + mt * 16 + ln;
            short8 a0 = *(const short8*)&w2[(size_t)ocr * 64 + lk];
            short8 a1 = *(const short8*)&w2[(size_t)ocr * 64 + 32 + lk];
            #pragma unroll
            for (int nt = 0; nt < 4; ++nt) {
                acc[mt][nt] = __builtin_amdgcn_mfma_f32_16x16x32_bf16(a0, b0v[nt], acc[mt][nt], 0, 0, 0);
                acc[mt][nt] = __builtin_amdgcn_mfma_f32_16x16x32_bf16(a1, b1v[nt], acc[mt][nt], 0, 0, 0);
            }
        }
        __syncthreads();   // h1s reads done (Ts alias safe later)
        #pragma unroll
        for (int mt = 0; mt < 4; ++mt) {
            int ocb = w * 64 + mt * 16 + lkg * 4;
            int chk = ocb >> 3, pos = (lkg & 1) * 4;
            float bv0 = b2[ocb + 0], bv1 = b2[ocb + 1], bv2 = b2[ocb + 2], bv3 = b2[ocb + 3];
            #pragma unroll
            for (int nt = 0; nt < 4; ++nt) {
                int pxl = nt * 16 + ln;
                short4v pk;
                pk[0] = (short)f2b(fmaxf(acc[mt][nt][0] + bv0, 0.f));
                pk[1] = (short)f2b(fmaxf(acc[mt][nt][1] + bv1, 0.f));
                pk[2] = (short)f2b(fmaxf(acc[mt][nt][2] + bv2, 0.f));
                pk[3] = (short)f2b(fmaxf(acc[mt][nt][3] + bv3, 0.f));
                *(short4v*)&h2s[chk * 512 + pxl * 8 + pos] = pk;
            }
        }
    }
    __syncthreads();     // h2s ready
    // ---- layer 3: one 192-row chunk (in-loop L2-hot weight loads)
    const int rowbase = chain ? 576 : u * 192;   // row into w33
    const int obase   = chain ? 0 : u * 192;     // row into output
    const float* b3 = chain ? b3B : b3A;
    unsigned short* outp = chain ? outB : outA;
    float4v acc[3][4] = {};
    const int r0 = rowbase + w * 48 + ln;
    #pragma unroll
    for (int kc = 0; kc < 8; ++kc) {
        short8 a0 = *(const short8*)&w33[(size_t)(r0 +  0) * 256 + kc * 32 + lk];
        short8 a1 = *(const short8*)&w33[(size_t)(r0 + 16) * 256 + kc * 32 + lk];
        short8 a2 = *(const short8*)&w33[(size_t)(r0 + 32) * 256 + kc * 32 + lk];
        #pragma unroll
        for (int nt = 0; nt < 4; ++nt) {
            short8 b = *(const short8*)&h2s[(kc * 4 + lkg) * 512 + (nt * 16 + ln) * 8];
            acc[0][nt] = __builtin_amdgcn_mfma_f32_16x16x32_bf16(a0, b, acc[0][nt], 0, 0, 0);
            acc[1][nt] = __builtin_amdgcn_mfma_f32_16x16x32_bf16(a1, b, acc[1][nt], 0, 0, 0);
            acc[2][nt] = __builtin_amdgcn_mfma_f32_16x16x32_bf16(a2, b, acc[2][nt], 0, 0, 0);
        }
    }
    // ---- epilogue: per-mt 64-row transpose through Ts (aliases h1s), coalesced stores
    #pragma unroll
    for (int mt = 0; mt < 3; ++mt) {
        __syncthreads();
        {
            int tr = w * 16 + lkg * 4;
            #pragma unroll
            for (int r = 0; r < 4; ++r) {
                float bv = b3[obase + w * 48 + mt * 16 + lkg * 4 + r];
                #pragma unroll
                for (int nt = 0; nt < 4; ++nt)
                    Ts[(tr + r) * 72 + nt * 16 + ln] = f2b(acc[mt][nt][r] + bv);
            }
        }
        __syncthreads();
        for (int i = tid; i < 512; i += 256) {
            int row = i >> 3, pc = (i & 7) * 8;
            int gr = obase + (row >> 4) * 48 + mt * 16 + (row & 15);
            *(short8*)&outp[(size_t)gr * NPIX + px0 + pc] = *(const short8*)&Ts[row * 72 + pc];
        }
    }
}

// ---------------------------------------------------------------- bf16 MFMA 3x3 conv, 2-row tiles
template<int MT>
__global__ __launch_bounds__(256) void conv3x3_mfma(
    const unsigned short* __restrict__ act, const unsigned short* __restrict__ wgt,
    const float* __restrict__ bias, unsigned short* __restrict__ out,
    int relu)
{
    constexpr int SP = 72;
    constexpr int OCP = MT * 16;
    __shared__ unsigned short Bs[4 * 66 * SP];   // 38016 B
    const int tid = threadIdx.x;
    int bx = blockIdx.x;
    const int xt = bx % 3; bx /= 3;
    const int yg = bx % 96; const int b = bx / 96;
    const int y0 = yg * 2;
    const int x0 = xt * 64;
    const size_t actb = (size_t)b * NPIX * 64;
    const int w = tid >> 6, l = tid & 63;
    const int ln = l & 15, lkg = l >> 4, lk = lkg * 8;
    const int mt = (MT == 4) ? w : 0;
    short8 Wr[9][2];
    #pragma unroll
    for (int t = 0; t < 9; ++t)
        #pragma unroll
        for (int hh = 0; hh < 2; ++hh)
            Wr[t][hh] = *(const short8*)&wgt[((size_t)t * OCP + mt * 16 + ln) * 64 + hh * 32 + lk];
    for (int s = tid; s < 264; s += 256) {
        int r = s / 66, i = s % 66;
        int yy = y0 + r - 1, xx = x0 + i - 1;
        unsigned short* dst = &Bs[(r * 66 + i) * SP];
        if (yy >= 0 && yy < 192 && xx >= 0 && xx < 192) {
            const unsigned short* src = &act[actb + (size_t)(yy * 192 + xx) * 64];
            #pragma unroll
            for (int j = 0; j < 8; ++j) *(short8*)(dst + j * 8) = *(const short8*)(src + j * 8);
        } else {
            short8 z = {};
            #pragma unroll
            for (int j = 0; j < 8; ++j) *(short8*)(dst + j * 8) = z;
        }
    }
    __syncthreads();
    const int NT = (MT == 4) ? 4 : 1;
    const int ntb = (MT == 4) ? 0 : w;
    float4v acc[2][4] = {};
    #pragma unroll
    for (int t = 0; t < 9; ++t) {
        const int r = t / 3, dx = t % 3;
        #pragma unroll
        for (int hh = 0; hh < 2; ++hh) {
            #pragma unroll
            for (int o = 0; o < 2; ++o) {
                #pragma unroll
                for (int n = 0; n < 4; ++n) {
                    if (n >= NT) break;
                    int slot = (o + r) * 66 + (ntb + n) * 16 + ln + dx;
                    short8 bf = *(const short8*)&Bs[slot * SP + hh * 32 + lk];
                    acc[o][n] = __builtin_amdgcn_mfma_f32_16x16x32_bf16(Wr[t][hh], bf, acc[o][n], 0, 0, 0);
                }
            }
        }
    }
    #pragma unroll
    for (int o = 0; o < 2; ++o) {
        #pragma unroll
        for (int n = 0; n < 4; ++n) {
            if (n >= NT) break;
            int px = (y0 + o) * 192 + x0 + (ntb + n) * 16 + ln;
            if (MT == 4) {
                int oc = mt * 16 + lkg * 4;
                float v0 = acc[o][n][0] + bias[oc + 0];
                float v1 = acc[o][n][1] + bias[oc + 1];
                float v2 = acc[o][n][2] + bias[oc + 2];
                float v3 = acc[o][n][3] + bias[oc + 3];
                if (relu) { v0 = fmaxf(v0, 0.f); v1 = fmaxf(v1, 0.f); v2 = fmaxf(v2, 0.f); v3 = fmaxf(v3, 0.f); }
                uint2 pk;
                pk.x = (unsigned int)f2b(v0) | (((unsigned int)f2b(v1)) << 16);
                pk.y = (unsigned int)f2b(v2) | (((unsigned int)f2b(v3)) << 16);
                *(uint2*)&out[((size_t)b * NPIX + px) * 64 + oc] = pk;
            } else if (lkg == 0) {
                float v0 = acc[o][n][0] + bias[0];
                float v1 = acc[o][n][1] + bias[1];
                out[((size_t)b * 2 + 0) * NPIX + px] = f2b(v0);
                out[((size_t)b * 2 + 1) * NPIX + px] = f2b(v1);
            }
        }
    }
}

// ---------------------------------------------------------------- mean: single-plane LDS, sequential b
// LDS 20.4 KB -> 7 blocks/CU. b-invariant softmax weights precomputed in registers.
#define PLSZ 10192   // 98*104
__global__ __launch_bounds__(256) void mean_k(
    const unsigned short* __restrict__ xb, const int* __restrict__ imy, const int* __restrict__ imx,
    const unsigned short* __restrict__ dw, unsigned short* __restrict__ mean_cm)
{
    __shared__ unsigned short pl[PLSZ];
    const int c = blockIdx.y;
    const int px0 = blockIdx.x * 1024;
    const int tid = threadIdx.x;
    {   // zero once; borders stay zero across both stages (restage touches interior only)
        short8 z = {};
        short8* pf = (short8*)pl;
        for (int i = tid; i < PLSZ / 8; i += 256) pf[i] = z;
    }
    float wk[4][9];
    int base[4];
    #pragma unroll
    for (int q = 0; q < 4; ++q) {
        int px = px0 + q * 256 + tid;
        base[q] = imy[px] * 104 + imx[px] + 3;
        float d[9];
        #pragma unroll
        for (int k = 0; k < 9; ++k) d[k] = b2f(dw[(size_t)(c * 9 + k) * NPIX + px]);
        float m = d[0];
        #pragma unroll
        for (int k = 1; k < 9; ++k) m = fmaxf(m, d[k]);
        float s = 0.f;
        #pragma unroll
        for (int k = 0; k < 9; ++k) { wk[q][k] = __expf(d[k] - m); s += wk[q][k]; }
        float inv = 1.f / s;
        #pragma unroll
        for (int k = 0; k < 9; ++k) wk[q][k] *= inv;
    }
    #pragma unroll
    for (int b = 0; b < 2; ++b) {
        __syncthreads();   // zero done (b=0) / prior reads done (b=1)
        const unsigned short* xp = xb + (size_t)(b * 64 + c) * 9216;
        for (int i = tid; i < 96 * 12; i += 256) {
            int row = i / 12, ch = i % 12;
            const short4v* src = (const short4v*)&xp[row * 96 + ch * 8];
            unsigned short* dd = &pl[(row + 1) * 104 + 4 + ch * 8];
            *(short4v*)dd = src[0];
            *(short4v*)(dd + 4) = src[1];
        }
        __syncthreads();
        #pragma unroll
        for (int q = 0; q < 4; ++q) {
            int px = px0 + q * 256 + tid;
            float a = 0.f;
            #pragma unroll
            for (int k = 0; k < 9; ++k)
                a += wk[q][k] * b2f(pl[base[q] + (k / 3) * 104 + (k % 3)]);
            mean_cm[(size_t)(b * 64 + c) * NPIX + px] = f2b(a);
        }
    }
}

// ---------------------------------------------------------------- transpose [2][64][NPIX] -> [2][NPIX][64]
__global__ __launch_bounds__(256) void tr_k(
    const unsigned short* __restrict__ in, unsigned short* __restrict__ out)
{
    __shared__ unsigned short T[64 * 68];
    int px0 = blockIdx.x * 64;
    int b = blockIdx.y;
    int tid = threadIdx.x;
    for (int i = tid; i < 4096; i += 256) {
        int c = i >> 6, p = i & 63;
        T[p * 68 + c] = in[(size_t)(b * 64 + c) * NPIX + px0 + p];
    }
    __syncthreads();
    for (int i = tid; i < 4096; i += 256) {
        int p = i >> 6, c = i & 63;
        out[((size_t)b * NPIX + px0 + p) * 64 + c] = T[p * 68 + c];
    }
}

// ---------------------------------------------------------------- xa: single-plane LDS, sequential b
__global__ __launch_bounds__(256) void xa_k(
    const unsigned short* __restrict__ xb, const int* __restrict__ imy, const int* __restrict__ imx,
    const unsigned short* __restrict__ dw, const unsigned short* __restrict__ mean_cm,
    const unsigned short* __restrict__ sigma, unsigned short* __restrict__ xab)
{
    __shared__ unsigned short pl[PLSZ];
    const int c = blockIdx.y;
    const int px0 = blockIdx.x * 1024;
    const int tid = threadIdx.x;
    {
        short8 z = {};
        short8* pf = (short8*)pl;
        for (int i = tid; i < PLSZ / 8; i += 256) pf[i] = z;
    }
    float d[4][9];
    int base[4];
    #pragma unroll
    for (int q = 0; q < 4; ++q) {
        int px = px0 + q * 256 + tid;
        base[q] = imy[px] * 104 + imx[px] + 3;
        #pragma unroll
        for (int k = 0; k < 9; ++k) d[q][k] = b2f(dw[(size_t)(c * 9 + k) * NPIX + px]);
    }
    #pragma unroll
    for (int b = 0; b < 2; ++b) {
        __syncthreads();
        const unsigned short* xp = xb + (size_t)(b * 64 + c) * 9216;
        for (int i = tid; i < 96 * 12; i += 256) {
            int row = i / 12, ch = i % 12;
            const short4v* src = (const short4v*)&xp[row * 96 + ch * 8];
            unsigned short* dd = &pl[(row + 1) * 104 + 4 + ch * 8];
            *(short4v*)dd = src[0];
            *(short4v*)(dd + 4) = src[1];
        }
        __syncthreads();
        #pragma unroll
        for (int q = 0; q < 4; ++q) {
            int px = px0 + q * 256 + tid;
            float mn = b2f(mean_cm[(size_t)(b * 64 + c) * NPIX + px]);
            float sd = b2f(sigma[((size_t)b * 2 + 0) * NPIX + px]);
            float sr = b2f(sigma[((size_t)b * 2 + 1) * NPIX + px]);
            float h[9], bw[9];
            #pragma unroll
            for (int k = 0; k < 9; ++k) {
                h[k] = b2f(pl[base[q] + (k / 3) * 104 + (k % 3)]);
                bw[k] = sd * d[q][k] + sr * fabsf(h[k] - mn);
            }
            float m = bw[0];
            #pragma unroll
            for (int k = 1; k < 9; ++k) m = fmaxf(m, bw[k]);
            float s = 0.f, a = 0.f;
            #pragma unroll
            for (int k = 0; k < 9; ++k) { float e = __expf(bw[k] - m); s += e; a += e * h[k]; }
            xab[(size_t)(b * 64 + c) * NPIX + px] = f2b(a / s);
        }
    }
}

// ---------------------------------------------------------------- fused einsum: block = 64 px, 4 c-quarters
__global__ __launch_bounds__(256) void einsum_k(
    const unsigned short* __restrict__ xab, const unsigned short* __restrict__ pw,
    float* __restrict__ out)
{
    __shared__ float red[3][4][64];
    const int tid = threadIdx.x;
    const int pxl = tid & 63, cq = tid >> 6;
    const int px = blockIdx.x * 64 + pxl;
    const int b = blockIdx.y;
    float a0 = 0.f, a1 = 0.f, a2 = 0.f;
    #pragma unroll
    for (int ci = 0; ci < 16; ++ci) {
        int c = cq * 16 + ci;
        float v = b2f(xab[(size_t)(b * 64 + c) * NPIX + px]);
        a0 += v * b2f(pw[(size_t)(c * 3 + 0) * NPIX + px]);
        a1 += v * b2f(pw[(size_t)(c * 3 + 1) * NPIX + px]);
        a2 += v * b2f(pw[(size_t)(c * 3 + 2) * NPIX + px]);
    }
    red[0][cq][pxl] = a0;
    red[1][cq][pxl] = a1;
    red[2][cq][pxl] = a2;
    __syncthreads();
    if (cq < 3) {
        float s = red[cq][0][pxl] + red[cq][1][pxl] + red[cq][2][pxl] + red[cq][3][pxl];
        out[((size_t)b * 3 + cq) * NPIX + px] = s;
    }
}

extern "C" void kernel_launch(void* const* d_in, const int* in_sizes, int n_in,
                              void* d_out, int out_size, void* d_ws, size_t ws_size,
                              hipStream_t stream)
{
    (void)in_sizes; (void)n_in; (void)out_size; (void)ws_size;
    const float* x      = (const float*)d_in[0];
    const float* pose   = (const float*)d_in[1];
    const int*   imy    = (const int*)d_in[2];
    const int*   imx    = (const int*)d_in[3];
    const float* sig_w1 = (const float*)d_in[4];
    const float* sig_b1 = (const float*)d_in[5];
    const float* sig_w2 = (const float*)d_in[6];
    const float* sig_b2 = (const float*)d_in[7];
    const float* sig_w3 = (const float*)d_in[8];
    const float* sig_b3 = (const float*)d_in[9];
    const float* dw_w1  = (const float*)d_in[10];
    const float* dw_b1  = (const float*)d_in[11];
    const float* dw_w2  = (const float*)d_in[12];
    const float* dw_b2  = (const float*)d_in[13];
    const float* dw_w3  = (const float*)d_in[14];
    const float* dw_b3  = (const float*)d_in[15];
    const float* pw_w1  = (const float*)d_in[16];
    const float* pw_b1  = (const float*)d_in[17];
    const float* pw_w2  = (const float*)d_in[18];
    const float* pw_b2  = (const float*)d_in[19];
    const float* pw_w3  = (const float*)d_in[20];
    const float* pw_b3  = (const float*)d_in[21];
    float* out = (float*)d_out;

    unsigned short* ws = (unsigned short*)d_ws;
    size_t off = 0;
    unsigned short* wb      = ws + off; off += WB_TOTAL;
    unsigned short* xb16    = ws + off; off += (size_t)XCAST_N;
    unsigned short* dwbuf   = ws + off; off += (size_t)576 * NPIX;      // plane-major
    unsigned short* pwbuf   = ws + off; off += (size_t)192 * NPIX;      // plane-major
    unsigned short* mean_cm = ws + off; off += (size_t)2 * 64 * NPIX;
    unsigned short* mean_pm = ws + off; off += (size_t)2 * NPIX * 64;
    unsigned short* s1      = ws + off; off += (size_t)2 * NPIX * 64;
    unsigned short* s2      = ws + off; off += (size_t)2 * NPIX * 64;
    unsigned short* sigma   = ws + off; off += (size_t)2 * 2 * NPIX;
    unsigned short* xab     = ws + off; off += (size_t)2 * 64 * NPIX;

    unsigned short* w_dw2 = wb + 0;
    unsigned short* w_pw2 = wb + 16384;
    unsigned short* w_33  = wb + 32768;   // combined [768][256]
    unsigned short* w_s1t = wb + 229376;
    unsigned short* w_s2t = wb + 266240;
    unsigned short* w_s3t = wb + 303104;

    dim3 blk(256);
    prep_all<<<dim3((WB_TOTAL + XCAST_N + 255) / 256), blk, 0, stream>>>(
        dw_w2, dw_w3, pw_w2, pw_w3, sig_w1, sig_w2, sig_w3, wb, x, xb16);
    mlp_fused<<<dim3(576, 4), blk, 0, stream>>>(
        pose, dw_w1, dw_b1, pw_w1, pw_b1, w_dw2, w_pw2, dw_b2, pw_b2,
        w_33, dw_b3, pw_b3, dwbuf, pwbuf);
    mean_k<<<dim3(36, 64), blk, 0, stream>>>(xb16, imy, imx, dwbuf, mean_cm);
    tr_k<<<dim3(576, 2), blk, 0, stream>>>(mean_cm, mean_pm);
    conv3x3_mfma<4><<<dim3(576), blk, 0, stream>>>(mean_pm, w_s1t, sig_b1, s1, 1);
    conv3x3_mfma<4><<<dim3(576), blk, 0, stream>>>(s1,      w_s2t, sig_b2, s2, 1);
    conv3x3_mfma<1><<<dim3(576), blk, 0, stream>>>(s2,      w_s3t, sig_b3, sigma, 0);
    xa_k<<<dim3(36, 64), blk, 0, stream>>>(xb16, imy, imx, dwbuf, mean_cm, sigma, xab);
    einsum_k<<<dim3(576, 2), blk, 0, stream>>>(xab, pwbuf, out);
}